// Round 1
// 356.360 us; speedup vs baseline: 1.0063x; 1.0063x over previous
//
#include <hip/hip_runtime.h>
#include <hip/hip_bf16.h>

// ---------------------------------------------------------------------------
// GCN forward on MI355X — round 14.
// R13 evidence: bucketA 58us with HBM 15%, VALU 3.7%, Occupancy 17% -> NOT
// write-amp-bound (R12->R13 cut WRITE 53->37.5MB for only ~2us). It is
// latency-bound at 1 block/CU x 8 waves (grid 257). Fix: 1024 threads +
// TILE_A 8192 -> grid 513 -> 2 blocks/CU, up to 32 waves/CU. Accept slightly
// shorter write runs (21 el = 168B) since write BW is 10x underutilized.
// Same occupancy fix applied to bucketB (391 blocks x 512thr -> 1024thr).
// Everything else unchanged from R13.
// ---------------------------------------------------------------------------

#define HID 64
#define LAB 40
#define RSH 9          // 512 rows per bucket
#define KMAX 512       // max buckets (runtime K = 391)
#define TILE_A 8192    // elements per bucketA block (1024 threads x 8)

__device__ __forceinline__ float loadF(const void* p, size_t i, int bf16) {
    if (bf16) return __bfloat162float(((const __hip_bfloat16*)p)[i]);
    return ((const float*)p)[i];
}

__device__ __forceinline__ int loadI(const void* p, size_t i, int i64) {
    if (i64) return (int)(((const long long*)p)[i]);
    return ((const int*)p)[i];
}

// packed bf16x2 helpers
__device__ __forceinline__ float bflo(unsigned v) { return __uint_as_float(v << 16); }
__device__ __forceinline__ float bfhi(unsigned v) { return __uint_as_float(v & 0xFFFF0000u); }
__device__ __forceinline__ unsigned bfr16(float x) {
    unsigned u = __float_as_uint(x);
    return (u + 0x7FFFu + ((u >> 16) & 1u)) >> 16;
}
__device__ __forceinline__ unsigned bfpack(float lo, float hi) {
    return bfr16(lo) | (bfr16(hi) << 16);
}

// fp8 e4m3 HW converts
__device__ __forceinline__ unsigned fp8pack4(float a, float b, float c, float d) {
    int r = __builtin_amdgcn_cvt_pk_fp8_f32(a, b, 0, false);
    r = __builtin_amdgcn_cvt_pk_fp8_f32(c, d, r, true);
    return (unsigned)r;
}

// nontemporal int2 load (keep P streams out of L2)
__device__ __forceinline__ void ntload(const int2* P, int idx, int* c, float* w) {
    long long raw = __builtin_nontemporal_load((const long long*)P + idx);
    *c = (int)(unsigned)(raw & 0xFFFFFFFFll);
    *w = __int_as_float((int)(raw >> 32));
}

// dtype probe (validated R1-R13)
__global__ void probe_kernel(const void* b1p, const void* fidxp, int* flags) {
    if (threadIdx.x == 0 && blockIdx.x == 0) {
        const unsigned short* u = (const unsigned short*)b1p;
        int bf16 = 1;
        for (int i = 0; i < 64; i += 2)
            if ((unsigned short)(u[i] & 0x7FFF) >= 0x3E80) { bf16 = 0; break; }
        const int* ip = (const int*)fidxp;
        int i64 = 1;
        for (int i = 1; i < 128; i += 2)
            if (ip[i] != 0) { i64 = 0; break; }
        flags[0] = bf16; flags[1] = i64; flags[2] = 0; flags[3] = 0;
    }
}

__global__ void zero_kernel(int4* p, int n4) {
    int i = blockIdx.x * blockDim.x + threadIdx.x;
    if (i < n4) p[i] = make_int4(0, 0, 0, 0);
}

// W1 -> packed bf16 staging: entry i = features 4i..4i+3 (uint2)
__global__ void convw1_kernel(const void* W1, uint2* w1q, const int* flags, int ne) {
    int i = blockIdx.x * blockDim.x + threadIdx.x;
    if (i < ne) {
        float f0 = loadF(W1, (size_t)4 * i,     flags[0]);
        float f1 = loadF(W1, (size_t)4 * i + 1, flags[0]);
        float f2 = loadF(W1, (size_t)4 * i + 2, flags[0]);
        float f3 = loadF(W1, (size_t)4 * i + 3, flags[0]);
        w1q[i] = make_uint2(bfpack(f0, f1), bfpack(f2, f3));
    }
}

// LDS-privatized bucket histogram (grid-stride)
__global__ void histB_kernel(const void* fidx, const void* eidx, int* cntB,
                             const int* flags, int nnz, int nE, int N, int nb) {
    __shared__ int lh[KMAX];
    for (int t = threadIdx.x; t < KMAX; t += 256) lh[t] = 0;
    __syncthreads();
    const int i64 = flags[1];
    const int nT = nnz + nE;
    for (int i = blockIdx.x * 256 + threadIdx.x; i < nT; i += nb * 256) {
        int grow = (i < nnz) ? loadI(fidx, (size_t)i, i64)
                             : N + loadI(eidx, (size_t)(i - nnz), i64);
        atomicAdd(&lh[grow >> RSH], 1);
    }
    __syncthreads();
    for (int t = threadIdx.x; t < KMAX; t += 256) {
        int c = lh[t];
        if (c) atomicAdd(&cntB[t], c);
    }
}

// single-block exclusive scan of bucket counts -> bqstart + bq cursors
__global__ void scanB_kernel(const int* cntB, int* bqstart, int* bq, int K) {
    __shared__ int s[KMAX];
    int t = threadIdx.x;
    int x = (t < K) ? cntB[t] : 0;
    s[t] = x;
    __syncthreads();
    for (int off = 1; off < KMAX; off <<= 1) {
        int v = (t >= off) ? s[t - off] : 0;
        __syncthreads();
        s[t] += v;
        __syncthreads();
    }
    if (t < K) { int st = s[t] - x; bqstart[t] = st; bq[t] = st; }
}

// Pass A: bucket-grouped scatter into Q. 1024 threads, TILE_A=8192, rank-free
// (phase 3 recomputes rank via second LDS histogram pass). 2 blocks/CU.
__global__ __launch_bounds__(1024)
void bucketA_kernel(const void* fidx, const void* fval,
                    const void* eidx, const void* ew,
                    const int* flags, int* bq, int2* Q,
                    int nnz, int nE, int N) {
    __shared__ int hist[KMAX];
    __shared__ int gbase[KMAX];
    const int i64 = flags[1], bf16 = flags[0];
    const int nT = nnz + nE;
    const int base = blockIdx.x * TILE_A;
    if (threadIdx.x < KMAX) hist[threadIdx.x] = 0;
    __syncthreads();
    // phase 1: block-local bucket histogram
#pragma unroll 4
    for (int k = 0; k < TILE_A / 1024; k++) {
        int i = base + k * 1024 + threadIdx.x;
        if (i < nT) {
            int grow = (i < nnz) ? loadI(fidx, (size_t)i, i64)
                                 : N + loadI(eidx, (size_t)(i - nnz), i64);
            atomicAdd(&hist[grow >> RSH], 1);
        }
    }
    __syncthreads();
    // phase 2: reserve per-bucket runs; reset hist as rank cursors
    if (threadIdx.x < KMAX) {
        int c = hist[threadIdx.x];
        gbase[threadIdx.x] = c ? atomicAdd(&bq[threadIdx.x], c) : 0;
        hist[threadIdx.x] = 0;
    }
    __syncthreads();
    // phase 3: re-read row+col+val, recompute rank, bucket-grouped write
#pragma unroll 4
    for (int k = 0; k < TILE_A / 1024; k++) {
        int i = base + k * 1024 + threadIdx.x;
        if (i < nT) {
            int grow, c; float v;
            if (i < nnz) {
                grow = loadI(fidx, (size_t)i, i64);
                c    = loadI(fidx, (size_t)nnz + i, i64);
                v    = loadF(fval, (size_t)i, bf16);
            } else {
                int j = i - nnz;
                grow = N + loadI(eidx, (size_t)j, i64);
                c    = loadI(eidx, (size_t)nE + j, i64);
                v    = loadF(ew, (size_t)j, bf16);
            }
            int b = grow >> RSH;
            int rank = atomicAdd(&hist[b], 1);
            Q[gbase[b] + rank] = make_int2(((grow & ((1 << RSH) - 1)) << 17) | c,
                                           __float_as_int(v));
        }
    }
}

// Pass B: one 1024-thread block per bucket; LDS row hist + scan -> rp segment,
// scatter to P with LDS rank cursors. Scan is 512-wide (rows/bucket), guarded.
__global__ __launch_bounds__(1024)
void bucketB_kernel(const int2* Q, const int* bqstart, int* rp,
                    int2* P, int nT, int K) {
    __shared__ int lh[1 << RSH];
    __shared__ int s[1 << RSH];
    __shared__ int lstart[1 << RSH];
    const int b = blockIdx.x;
    const int t = threadIdx.x;
    const int start = bqstart[b];
    const int end = (b == K - 1) ? nT : bqstart[b + 1];
    if (t < (1 << RSH)) lh[t] = 0;
    __syncthreads();
    for (int i = start + t; i < end; i += 1024)
        atomicAdd(&lh[((unsigned)Q[i].x) >> 17], 1);
    __syncthreads();
    int x = (t < (1 << RSH)) ? lh[t] : 0;
    if (t < (1 << RSH)) s[t] = x;
    __syncthreads();
    for (int off = 1; off < (1 << RSH); off <<= 1) {
        int v = (t >= off && t < (1 << RSH)) ? s[t - off] : 0;
        __syncthreads();
        if (t < (1 << RSH)) s[t] += v;
        __syncthreads();
    }
    if (t < (1 << RSH)) {
        int rowstart = start + s[t] - x;
        rp[(b << RSH) + t] = rowstart;
        lstart[t] = rowstart;
        lh[t] = 0;
    }
    __syncthreads();
    for (int i = start + t; i < end; i += 1024) {
        int2 el = Q[i];
        int lr = ((unsigned)el.x) >> 17;
        int rank = atomicAdd(&lh[lr], 1);
        P[lstart[lr] + rank] = make_int2(el.x & 0x1FFFF, el.y);
    }
}

// 4 rows/wave feat gather: h = b1 + sum v*W1[c], stored fp8 (row*16+gl dword).
__global__ void gather_feat_kernel(const int* rp, const int2* P,
                                   const uint2* w1q, const void* b1,
                                   unsigned* hF8, const int* flags, int N) {
    int bf16 = flags[0];
    int wave = (blockIdx.x * blockDim.x + threadIdx.x) >> 6;
    int lane = threadIdx.x & 63;
    int g = lane >> 4, gl = lane & 15;
    int row = 4 * wave + g;
    int s = 0, e = 0;
    if (row < N) { s = rp[row]; e = rp[row + 1]; }
    float a0 = loadF(b1, (size_t)4 * gl,     bf16);
    float a1 = loadF(b1, (size_t)4 * gl + 1, bf16);
    float a2 = loadF(b1, (size_t)4 * gl + 2, bf16);
    float a3 = loadF(b1, (size_t)4 * gl + 3, bf16);
    const int sb = g << 4;
    for (int base = s; base < e; base += 16) {
        int idx = base + gl;
        int cl = 0; float vl = 0.f;
        if (idx < e) ntload(P, idx, &cl, &vl);
        int cnt = min(16, e - base);
        int j = 0;
        for (; j + 4 <= cnt; j += 4) {
            int   c0 = __shfl(cl, sb + j),     c1 = __shfl(cl, sb + j + 1);
            int   c2 = __shfl(cl, sb + j + 2), c3 = __shfl(cl, sb + j + 3);
            float v0 = __shfl(vl, sb + j),     v1 = __shfl(vl, sb + j + 1);
            float v2 = __shfl(vl, sb + j + 2), v3 = __shfl(vl, sb + j + 3);
            uint2 u0 = w1q[c0 * 16 + gl];
            uint2 u1 = w1q[c1 * 16 + gl];
            uint2 u2 = w1q[c2 * 16 + gl];
            uint2 u3 = w1q[c3 * 16 + gl];
            a0 += v0 * bflo(u0.x); a1 += v0 * bfhi(u0.x);
            a2 += v0 * bflo(u0.y); a3 += v0 * bfhi(u0.y);
            a0 += v1 * bflo(u1.x); a1 += v1 * bfhi(u1.x);
            a2 += v1 * bflo(u1.y); a3 += v1 * bfhi(u1.y);
            a0 += v2 * bflo(u2.x); a1 += v2 * bfhi(u2.x);
            a2 += v2 * bflo(u2.y); a3 += v2 * bfhi(u2.y);
            a0 += v3 * bflo(u3.x); a1 += v3 * bfhi(u3.x);
            a2 += v3 * bflo(u3.y); a3 += v3 * bfhi(u3.y);
        }
        for (; j < cnt; j++) {
            int   c = __shfl(cl, sb + j);
            float v = __shfl(vl, sb + j);
            uint2 u = w1q[c * 16 + gl];
            a0 += v * bflo(u.x); a1 += v * bfhi(u.x);
            a2 += v * bflo(u.y); a3 += v * bfhi(u.y);
        }
    }
    if (row < N) hF8[row * 16 + gl] = fp8pack4(a0, a1, a2, a3);
}

// Merged propagation, NO epilogue: h2 = relu(A @ h), fp8 in / fp8 out.
__global__ void gather_edge_h2_kernel(const int* rp, const int2* P,
                                      const unsigned* hF8, unsigned* h2F8,
                                      int N) {
    int wave = (blockIdx.x * blockDim.x + threadIdx.x) >> 6;
    int lane = threadIdx.x & 63;
    int g = lane >> 4, gl = lane & 15;
    int row = 4 * wave + g;
    int s = 0, e = 0;
    if (row < N) { s = rp[N + row]; e = rp[N + row + 1]; }
    float a0 = 0.f, a1 = 0.f, a2 = 0.f, a3 = 0.f;
    const int sb = g << 4;
    for (int base = s; base < e; base += 16) {
        int idx = base + gl;
        int cl = 0; float wl = 0.f;
        if (idx < e) ntload(P, idx, &cl, &wl);
        int cnt = min(16, e - base);
        int j = 0;
        for (; j + 8 <= cnt; j += 8) {
            int   c0 = __shfl(cl, sb + j),     c1 = __shfl(cl, sb + j + 1);
            int   c2 = __shfl(cl, sb + j + 2), c3 = __shfl(cl, sb + j + 3);
            int   c4 = __shfl(cl, sb + j + 4), c5 = __shfl(cl, sb + j + 5);
            int   c6 = __shfl(cl, sb + j + 6), c7 = __shfl(cl, sb + j + 7);
            float w0 = __shfl(wl, sb + j),     w1 = __shfl(wl, sb + j + 1);
            float w2 = __shfl(wl, sb + j + 2), w3 = __shfl(wl, sb + j + 3);
            float w4 = __shfl(wl, sb + j + 4), w5 = __shfl(wl, sb + j + 5);
            float w6 = __shfl(wl, sb + j + 6), w7 = __shfl(wl, sb + j + 7);
            int u0 = (int)hF8[c0 * 16 + gl];
            int u1 = (int)hF8[c1 * 16 + gl];
            int u2 = (int)hF8[c2 * 16 + gl];
            int u3 = (int)hF8[c3 * 16 + gl];
            int u4 = (int)hF8[c4 * 16 + gl];
            int u5 = (int)hF8[c5 * 16 + gl];
            int u6 = (int)hF8[c6 * 16 + gl];
            int u7 = (int)hF8[c7 * 16 + gl];
            a0 += w0 * __builtin_amdgcn_cvt_f32_fp8(u0, 0);
            a1 += w0 * __builtin_amdgcn_cvt_f32_fp8(u0, 1);
            a2 += w0 * __builtin_amdgcn_cvt_f32_fp8(u0, 2);
            a3 += w0 * __builtin_amdgcn_cvt_f32_fp8(u0, 3);
            a0 += w1 * __builtin_amdgcn_cvt_f32_fp8(u1, 0);
            a1 += w1 * __builtin_amdgcn_cvt_f32_fp8(u1, 1);
            a2 += w1 * __builtin_amdgcn_cvt_f32_fp8(u1, 2);
            a3 += w1 * __builtin_amdgcn_cvt_f32_fp8(u1, 3);
            a0 += w2 * __builtin_amdgcn_cvt_f32_fp8(u2, 0);
            a1 += w2 * __builtin_amdgcn_cvt_f32_fp8(u2, 1);
            a2 += w2 * __builtin_amdgcn_cvt_f32_fp8(u2, 2);
            a3 += w2 * __builtin_amdgcn_cvt_f32_fp8(u2, 3);
            a0 += w3 * __builtin_amdgcn_cvt_f32_fp8(u3, 0);
            a1 += w3 * __builtin_amdgcn_cvt_f32_fp8(u3, 1);
            a2 += w3 * __builtin_amdgcn_cvt_f32_fp8(u3, 2);
            a3 += w3 * __builtin_amdgcn_cvt_f32_fp8(u3, 3);
            a0 += w4 * __builtin_amdgcn_cvt_f32_fp8(u4, 0);
            a1 += w4 * __builtin_amdgcn_cvt_f32_fp8(u4, 1);
            a2 += w4 * __builtin_amdgcn_cvt_f32_fp8(u4, 2);
            a3 += w4 * __builtin_amdgcn_cvt_f32_fp8(u4, 3);
            a0 += w5 * __builtin_amdgcn_cvt_f32_fp8(u5, 0);
            a1 += w5 * __builtin_amdgcn_cvt_f32_fp8(u5, 1);
            a2 += w5 * __builtin_amdgcn_cvt_f32_fp8(u5, 2);
            a3 += w5 * __builtin_amdgcn_cvt_f32_fp8(u5, 3);
            a0 += w6 * __builtin_amdgcn_cvt_f32_fp8(u6, 0);
            a1 += w6 * __builtin_amdgcn_cvt_f32_fp8(u6, 1);
            a2 += w6 * __builtin_amdgcn_cvt_f32_fp8(u6, 2);
            a3 += w6 * __builtin_amdgcn_cvt_f32_fp8(u6, 3);
            a0 += w7 * __builtin_amdgcn_cvt_f32_fp8(u7, 0);
            a1 += w7 * __builtin_amdgcn_cvt_f32_fp8(u7, 1);
            a2 += w7 * __builtin_amdgcn_cvt_f32_fp8(u7, 2);
            a3 += w7 * __builtin_amdgcn_cvt_f32_fp8(u7, 3);
        }
        for (; j < cnt; j++) {
            int   c = __shfl(cl, sb + j);
            float w = __shfl(wl, sb + j);
            int u = (int)hF8[c * 16 + gl];
            a0 += w * __builtin_amdgcn_cvt_f32_fp8(u, 0);
            a1 += w * __builtin_amdgcn_cvt_f32_fp8(u, 1);
            a2 += w * __builtin_amdgcn_cvt_f32_fp8(u, 2);
            a3 += w * __builtin_amdgcn_cvt_f32_fp8(u, 3);
        }
    }
    if (row < N)
        h2F8[row * 16 + gl] = fp8pack4(fmaxf(a0, 0.f), fmaxf(a1, 0.f),
                                       fmaxf(a2, 0.f), fmaxf(a3, 0.f));
}

// Shuffle-free, LDS-free dense: z = relu_h2 @ W2 + b2, fp8 out.
__global__ void dense_kernel(const unsigned* h2F8, const void* W2, const void* b2,
                             unsigned char* zb, const int* flags, int N) {
    int bf16 = flags[0];
    int wave = (int)((blockIdx.x * blockDim.x + threadIdx.x) >> 6);
    int lane = threadIdx.x & 63;
    int jj = (lane < LAB) ? lane : 0;
    float w2c[HID];
#pragma unroll
    for (int k = 0; k < HID; k++) w2c[k] = loadF(W2, (size_t)k * LAB + jj, bf16);
    float bias = loadF(b2, (size_t)jj, bf16);
    int r0 = wave * 32;
    int r1 = min(r0 + 32, N);
    for (int r = r0; r < r1; r++) {
        const unsigned* hr = h2F8 + (size_t)r * 16;
        float acc = bias;
#pragma unroll
        for (int k16 = 0; k16 < 16; k16++) {
            int d = (int)hr[k16];
            acc += __builtin_amdgcn_cvt_f32_fp8(d, 0) * w2c[4 * k16];
            acc += __builtin_amdgcn_cvt_f32_fp8(d, 1) * w2c[4 * k16 + 1];
            acc += __builtin_amdgcn_cvt_f32_fp8(d, 2) * w2c[4 * k16 + 2];
            acc += __builtin_amdgcn_cvt_f32_fp8(d, 3) * w2c[4 * k16 + 3];
        }
        if (lane < LAB) {
            int pk = __builtin_amdgcn_cvt_pk_fp8_f32(acc, acc, 0, false);
            zb[(size_t)r * LAB + lane] = (unsigned char)(pk & 0xFF);
        }
    }
}

// 4 rows/wave: z2 = A@z (fp8 gather), fused log_softmax -> out.
__global__ void gather_edge_lsm_kernel(const int* rp, const int2* P,
                                       const unsigned* zF8, void* out,
                                       const int* flags, int N) {
    int bf16 = flags[0];
    int wave = (blockIdx.x * blockDim.x + threadIdx.x) >> 6;
    int lane = threadIdx.x & 63;
    int g = lane >> 4, gl = lane & 15;
    int row = 4 * wave + g;
    int s = 0, e = 0;
    if (row < N) { s = rp[N + row]; e = rp[N + row + 1]; }
    float a0 = 0.f, a1 = 0.f, a2 = 0.f, a3 = 0.f;
    const int sb = g << 4;
    const int act = (gl < 10);
    for (int base = s; base < e; base += 16) {
        int idx = base + gl;
        int cl = 0; float wl = 0.f;
        if (idx < e) ntload(P, idx, &cl, &wl);
        int cnt = min(16, e - base);
        int j = 0;
        for (; j + 4 <= cnt; j += 4) {
            int   c0 = __shfl(cl, sb + j),     c1 = __shfl(cl, sb + j + 1);
            int   c2 = __shfl(cl, sb + j + 2), c3 = __shfl(cl, sb + j + 3);
            float w0 = __shfl(wl, sb + j),     w1 = __shfl(wl, sb + j + 1);
            float w2 = __shfl(wl, sb + j + 2), w3 = __shfl(wl, sb + j + 3);
            if (act) {
                int u0 = (int)zF8[c0 * 10 + gl];
                int u1 = (int)zF8[c1 * 10 + gl];
                int u2 = (int)zF8[c2 * 10 + gl];
                int u3 = (int)zF8[c3 * 10 + gl];
                a0 += w0 * __builtin_amdgcn_cvt_f32_fp8(u0, 0);
                a1 += w0 * __builtin_amdgcn_cvt_f32_fp8(u0, 1);
                a2 += w0 * __builtin_amdgcn_cvt_f32_fp8(u0, 2);
                a3 += w0 * __builtin_amdgcn_cvt_f32_fp8(u0, 3);
                a0 += w1 * __builtin_amdgcn_cvt_f32_fp8(u1, 0);
                a1 += w1 * __builtin_amdgcn_cvt_f32_fp8(u1, 1);
                a2 += w1 * __builtin_amdgcn_cvt_f32_fp8(u1, 2);
                a3 += w1 * __builtin_amdgcn_cvt_f32_fp8(u1, 3);
                a0 += w2 * __builtin_amdgcn_cvt_f32_fp8(u2, 0);
                a1 += w2 * __builtin_amdgcn_cvt_f32_fp8(u2, 1);
                a2 += w2 * __builtin_amdgcn_cvt_f32_fp8(u2, 2);
                a3 += w2 * __builtin_amdgcn_cvt_f32_fp8(u2, 3);
                a0 += w3 * __builtin_amdgcn_cvt_f32_fp8(u3, 0);
                a1 += w3 * __builtin_amdgcn_cvt_f32_fp8(u3, 1);
                a2 += w3 * __builtin_amdgcn_cvt_f32_fp8(u3, 2);
                a3 += w3 * __builtin_amdgcn_cvt_f32_fp8(u3, 3);
            }
        }
        for (; j < cnt; j++) {
            int   c = __shfl(cl, sb + j);
            float w = __shfl(wl, sb + j);
            if (act) {
                int u = (int)zF8[c * 10 + gl];
                a0 += w * __builtin_amdgcn_cvt_f32_fp8(u, 0);
                a1 += w * __builtin_amdgcn_cvt_f32_fp8(u, 1);
                a2 += w * __builtin_amdgcn_cvt_f32_fp8(u, 2);
                a3 += w * __builtin_amdgcn_cvt_f32_fp8(u, 3);
            }
        }
    }
    float m = act ? fmaxf(fmaxf(a0, a1), fmaxf(a2, a3)) : -INFINITY;
#pragma unroll
    for (int off = 8; off; off >>= 1) m = fmaxf(m, __shfl_xor(m, off));
    float es = act ? (__expf(a0 - m) + __expf(a1 - m) + __expf(a2 - m) + __expf(a3 - m)) : 0.f;
#pragma unroll
    for (int off = 8; off; off >>= 1) es += __shfl_xor(es, off);
    float lse = m + __logf(es);
    if (act && row < N) {
        float o0 = a0 - lse, o1 = a1 - lse, o2 = a2 - lse, o3 = a3 - lse;
        if (bf16) {
            ((uint2*)out)[(size_t)row * 10 + gl] =
                make_uint2(bfpack(o0, o1), bfpack(o2, o3));
        } else {
            float4 v = make_float4(o0, o1, o2, o3);
            ((float4*)out)[(size_t)row * 10 + gl] = v;
        }
    }
}

extern "C" void kernel_launch(void* const* d_in, const int* in_sizes, int n_in,
                              void* d_out, int out_size, void* d_ws, size_t ws_size,
                              hipStream_t stream) {
    const void* fidx = d_in[0];
    const void* fval = d_in[1];
    const void* eidx = d_in[2];
    const void* ew   = d_in[3];
    const void* W1   = d_in[4];
    const void* b1   = d_in[5];
    const void* W2   = d_in[6];
    const void* b2   = d_in[7];

    const int nnz = in_sizes[1];          // 2,500,000
    const int nW1 = in_sizes[4];          // 2048*64
    const int nE  = in_sizes[3];          // 1,700,000
    const int N   = out_size / LAB;       // 100,000
    const int M   = 2 * N;
    const int nT  = nnz + nE;
    const int K   = (M + (1 << RSH) - 1) >> RSH;   // 391 buckets

    auto align256 = [](size_t x) { return (x + 255) & ~(size_t)255; };
    char* ws = (char*)d_ws;
    size_t off = 0;
    int*   flags   = (int*)(ws + off);   off += 256;
    // front: hF8 (6.4MB) | h2F8 (6.4MB) | zF8 (4MB); Q (int2, 33.6MB) overlays
    // front and dies before gather_feat writes hF8.
    char*  front   = ws + off;
    unsigned* hF8  = (unsigned*)front;                       // N*16 dwords
    unsigned* h2F8 = hF8 + (size_t)N * 16;                   // N*16 dwords
    unsigned char* zb = (unsigned char*)(h2F8 + (size_t)N * 16);  // N*40 B
    size_t frontBytes = (size_t)N * (64 + 64 + 40);
    size_t qBytes     = (size_t)nT * 8;
    off += align256(frontBytes > qBytes ? frontBytes : qBytes);
    int2*  P       = (int2*)(ws + off);  off += align256((size_t)nT * 8);
    int*   rp      = (int*)(ws + off);   off += align256(((size_t)KMAX << RSH) * 4 + 16);
    uint2* w1q     = (uint2*)(ws + off); off += align256((size_t)nW1 * 2);
    int*   cntB    = (int*)(ws + off);   off += KMAX * 4;
    int*   bqstart = (int*)(ws + off);   off += KMAX * 4;
    int*   bq      = (int*)(ws + off);   off += KMAX * 4;
    int2*  Q       = (int2*)front;

    // 1. dtype probe
    probe_kernel<<<1, 64, 0, stream>>>(b1, fidx, flags);

    // 2. zero bucket histogram; stage W1 packed
    zero_kernel<<<1, 256, 0, stream>>>((int4*)cntB, KMAX / 4);
    convw1_kernel<<<(nW1 / 4 + 255) / 256, 256, 0, stream>>>(W1, w1q, flags, nW1 / 4);

    // 3. bucket histogram (LDS-privatized)
    const int HB = 1024;
    histB_kernel<<<HB, 256, 0, stream>>>(fidx, eidx, cntB, flags, nnz, nE, N, HB);

    // 4. bucket scan -> starts + cursors
    scanB_kernel<<<1, KMAX, 0, stream>>>(cntB, bqstart, bq, K);

    // 5. pass A: bucket-grouped scatter into Q (8192-elem tiles, 1024 thr)
    bucketA_kernel<<<(nT + TILE_A - 1) / TILE_A, 1024, 0, stream>>>(
        fidx, fval, eidx, ew, flags, bq, Q, nnz, nE, N);

    // 6. pass B: per-bucket row hist/scan in LDS, rp segment, scatter -> P
    bucketB_kernel<<<K, 1024, 0, stream>>>(Q, bqstart, rp, P, nT, K);

    // 7. h = sparse_features @ W1 + b1 -> fp8
    int nwaves = (N + 3) / 4;
    int gblocks = (int)(((size_t)nwaves * 64 + 255) / 256);
    gather_feat_kernel<<<gblocks, 256, 0, stream>>>(rp, P, w1q, b1, hF8, flags, N);

    // 8. h2 = relu(A @ h) -> fp8 (gather-only, no epilogue)
    gather_edge_h2_kernel<<<gblocks, 256, 0, stream>>>(rp, P, hF8, h2F8, N);

    // 9. z = h2 @ W2 + b2 -> fp8 (shuffle-free dense)
    int dwaves = (N + 31) / 32;
    int dblocks = (dwaves * 64 + 255) / 256;
    dense_kernel<<<dblocks, 256, 0, stream>>>(h2F8, W2, b2, zb, flags, N);

    // 10. out = log_softmax(A @ z)
    gather_edge_lsm_kernel<<<gblocks, 256, 0, stream>>>(rp, P, (const unsigned*)zb,
                                                        d_out, flags, N);
}

// Round 2
// 343.390 us; speedup vs baseline: 1.0443x; 1.0378x over previous
//
#include <hip/hip_runtime.h>
#include <hip/hip_bf16.h>

// ---------------------------------------------------------------------------
// GCN forward on MI355X — round 15.
// R14 post-mortem: occupancy 17->58% but bucketA time UNCHANGED (57us) ->
// not wave-latency-bound. Neither pipe >18% -> cost is the per-element
// instruction/latency work of TWO full element passes (phase1 hist + phase3
// scatter) plus the blocking global atomicAdd between them. Fix: hoist
// phase1+2 into histB (re-tiled to bucketA's exact 513-block decomposition,
// emitting per-(bucket,block) counts cntPB = 512x513 ints, L2-resident) +
// tiny per-bucket scan kernel -> bucketA becomes phase-3-only (one element
// pass, no global atomic round-trip). Everything downstream unchanged.
// ---------------------------------------------------------------------------

#define HID 64
#define LAB 40
#define RSH 9          // 512 rows per bucket
#define KMAX 512       // max buckets (runtime K = 391)
#define TILE_A 8192    // elements per tile block (1024 threads x 8)

__device__ __forceinline__ float loadF(const void* p, size_t i, int bf16) {
    if (bf16) return __bfloat162float(((const __hip_bfloat16*)p)[i]);
    return ((const float*)p)[i];
}

__device__ __forceinline__ int loadI(const void* p, size_t i, int i64) {
    if (i64) return (int)(((const long long*)p)[i]);
    return ((const int*)p)[i];
}

// packed bf16x2 helpers
__device__ __forceinline__ float bflo(unsigned v) { return __uint_as_float(v << 16); }
__device__ __forceinline__ float bfhi(unsigned v) { return __uint_as_float(v & 0xFFFF0000u); }
__device__ __forceinline__ unsigned bfr16(float x) {
    unsigned u = __float_as_uint(x);
    return (u + 0x7FFFu + ((u >> 16) & 1u)) >> 16;
}
__device__ __forceinline__ unsigned bfpack(float lo, float hi) {
    return bfr16(lo) | (bfr16(hi) << 16);
}

// fp8 e4m3 HW converts
__device__ __forceinline__ unsigned fp8pack4(float a, float b, float c, float d) {
    int r = __builtin_amdgcn_cvt_pk_fp8_f32(a, b, 0, false);
    r = __builtin_amdgcn_cvt_pk_fp8_f32(c, d, r, true);
    return (unsigned)r;
}

// nontemporal int2 load (keep P streams out of L2)
__device__ __forceinline__ void ntload(const int2* P, int idx, int* c, float* w) {
    long long raw = __builtin_nontemporal_load((const long long*)P + idx);
    *c = (int)(unsigned)(raw & 0xFFFFFFFFll);
    *w = __int_as_float((int)(raw >> 32));
}

// dtype probe (validated R1-R14)
__global__ void probe_kernel(const void* b1p, const void* fidxp, int* flags) {
    if (threadIdx.x == 0 && blockIdx.x == 0) {
        const unsigned short* u = (const unsigned short*)b1p;
        int bf16 = 1;
        for (int i = 0; i < 64; i += 2)
            if ((unsigned short)(u[i] & 0x7FFF) >= 0x3E80) { bf16 = 0; break; }
        const int* ip = (const int*)fidxp;
        int i64 = 1;
        for (int i = 1; i < 128; i += 2)
            if (ip[i] != 0) { i64 = 0; break; }
        flags[0] = bf16; flags[1] = i64; flags[2] = 0; flags[3] = 0;
    }
}

__global__ void zero_kernel(int4* p, int n4) {
    int i = blockIdx.x * blockDim.x + threadIdx.x;
    if (i < n4) p[i] = make_int4(0, 0, 0, 0);
}

// W1 -> packed bf16 staging: entry i = features 4i..4i+3 (uint2)
__global__ void convw1_kernel(const void* W1, uint2* w1q, const int* flags, int ne) {
    int i = blockIdx.x * blockDim.x + threadIdx.x;
    if (i < ne) {
        float f0 = loadF(W1, (size_t)4 * i,     flags[0]);
        float f1 = loadF(W1, (size_t)4 * i + 1, flags[0]);
        float f2 = loadF(W1, (size_t)4 * i + 2, flags[0]);
        float f3 = loadF(W1, (size_t)4 * i + 3, flags[0]);
        w1q[i] = make_uint2(bfpack(f0, f1), bfpack(f2, f3));
    }
}

// Bucket histogram, tiled EXACTLY like bucketA (one block per TILE_A run).
// Emits per-(bucket,block) counts cntPB[b*nblk+blk] + global totals cntB.
__global__ __launch_bounds__(1024)
void histB_kernel(const void* fidx, const void* eidx, int* cntB, int* cntPB,
                  const int* flags, int nnz, int nE, int N, int nblk) {
    __shared__ int lh[KMAX];
    if (threadIdx.x < KMAX) lh[threadIdx.x] = 0;
    __syncthreads();
    const int i64 = flags[1];
    const int nT = nnz + nE;
    const int base = blockIdx.x * TILE_A;
#pragma unroll 4
    for (int k = 0; k < TILE_A / 1024; k++) {
        int i = base + k * 1024 + threadIdx.x;
        if (i < nT) {
            int grow = (i < nnz) ? loadI(fidx, (size_t)i, i64)
                                 : N + loadI(eidx, (size_t)(i - nnz), i64);
            atomicAdd(&lh[grow >> RSH], 1);
        }
    }
    __syncthreads();
    if (threadIdx.x < KMAX) {
        int c = lh[threadIdx.x];
        cntPB[(size_t)threadIdx.x * nblk + blockIdx.x] = c;
        if (c) atomicAdd(&cntB[threadIdx.x], c);
    }
}

// single-block exclusive scan of bucket counts -> bqstart
__global__ void scanB_kernel(const int* cntB, int* bqstart, int K) {
    __shared__ int s[KMAX];
    int t = threadIdx.x;
    int x = (t < K) ? cntB[t] : 0;
    s[t] = x;
    __syncthreads();
    for (int off = 1; off < KMAX; off <<= 1) {
        int v = (t >= off) ? s[t - off] : 0;
        __syncthreads();
        s[t] += v;
        __syncthreads();
    }
    if (t < K) bqstart[t] = s[t] - x;
}

// one block per bucket: exclusive scan over the nblk per-block counts,
// rebased by bqstart -> cntPB becomes absolute write base per (bucket,block)
__global__ __launch_bounds__(1024)
void scanPB_kernel(int* cntPB, const int* bqstart, int nblk) {
    __shared__ int s[1024];
    const int b = blockIdx.x;
    const int t = threadIdx.x;
    int x = (t < nblk) ? cntPB[(size_t)b * nblk + t] : 0;
    s[t] = x;
    __syncthreads();
    for (int off = 1; off < 1024; off <<= 1) {
        int v = (t >= off) ? s[t - off] : 0;
        __syncthreads();
        s[t] += v;
        __syncthreads();
    }
    if (t < nblk) cntPB[(size_t)b * nblk + t] = bqstart[b] + s[t] - x;
}

// Pass A: phase-3-only bucket-grouped scatter into Q. Write bases come
// precomputed from histB+scanPB; LDS hist is only the per-bucket rank cursor.
__global__ __launch_bounds__(1024)
void bucketA_kernel(const void* fidx, const void* fval,
                    const void* eidx, const void* ew,
                    const int* flags, const int* cntPB, int2* Q,
                    int nnz, int nE, int N, int nblk) {
    __shared__ int hist[KMAX];
    __shared__ int gbase[KMAX];
    const int i64 = flags[1], bf16 = flags[0];
    const int nT = nnz + nE;
    const int base = blockIdx.x * TILE_A;
    if (threadIdx.x < KMAX) {
        hist[threadIdx.x] = 0;
        gbase[threadIdx.x] = cntPB[(size_t)threadIdx.x * nblk + blockIdx.x];
    }
    __syncthreads();
#pragma unroll 4
    for (int k = 0; k < TILE_A / 1024; k++) {
        int i = base + k * 1024 + threadIdx.x;
        if (i < nT) {
            int grow, c; float v;
            if (i < nnz) {
                grow = loadI(fidx, (size_t)i, i64);
                c    = loadI(fidx, (size_t)nnz + i, i64);
                v    = loadF(fval, (size_t)i, bf16);
            } else {
                int j = i - nnz;
                grow = N + loadI(eidx, (size_t)j, i64);
                c    = loadI(eidx, (size_t)nE + j, i64);
                v    = loadF(ew, (size_t)j, bf16);
            }
            int b = grow >> RSH;
            int rank = atomicAdd(&hist[b], 1);
            Q[gbase[b] + rank] = make_int2(((grow & ((1 << RSH) - 1)) << 17) | c,
                                           __float_as_int(v));
        }
    }
}

// Pass B: one 1024-thread block per bucket; LDS row hist + scan -> rp segment,
// scatter to P with LDS rank cursors. Scan is 512-wide (rows/bucket), guarded.
__global__ __launch_bounds__(1024)
void bucketB_kernel(const int2* Q, const int* bqstart, int* rp,
                    int2* P, int nT, int K) {
    __shared__ int lh[1 << RSH];
    __shared__ int s[1 << RSH];
    __shared__ int lstart[1 << RSH];
    const int b = blockIdx.x;
    const int t = threadIdx.x;
    const int start = bqstart[b];
    const int end = (b == K - 1) ? nT : bqstart[b + 1];
    if (t < (1 << RSH)) lh[t] = 0;
    __syncthreads();
    for (int i = start + t; i < end; i += 1024)
        atomicAdd(&lh[((unsigned)Q[i].x) >> 17], 1);
    __syncthreads();
    int x = (t < (1 << RSH)) ? lh[t] : 0;
    if (t < (1 << RSH)) s[t] = x;
    __syncthreads();
    for (int off = 1; off < (1 << RSH); off <<= 1) {
        int v = (t >= off && t < (1 << RSH)) ? s[t - off] : 0;
        __syncthreads();
        if (t < (1 << RSH)) s[t] += v;
        __syncthreads();
    }
    if (t < (1 << RSH)) {
        int rowstart = start + s[t] - x;
        rp[(b << RSH) + t] = rowstart;
        lstart[t] = rowstart;
        lh[t] = 0;
    }
    __syncthreads();
    for (int i = start + t; i < end; i += 1024) {
        int2 el = Q[i];
        int lr = ((unsigned)el.x) >> 17;
        int rank = atomicAdd(&lh[lr], 1);
        P[lstart[lr] + rank] = make_int2(el.x & 0x1FFFF, el.y);
    }
}

// 4 rows/wave feat gather: h = b1 + sum v*W1[c], stored fp8 (row*16+gl dword).
__global__ void gather_feat_kernel(const int* rp, const int2* P,
                                   const uint2* w1q, const void* b1,
                                   unsigned* hF8, const int* flags, int N) {
    int bf16 = flags[0];
    int wave = (blockIdx.x * blockDim.x + threadIdx.x) >> 6;
    int lane = threadIdx.x & 63;
    int g = lane >> 4, gl = lane & 15;
    int row = 4 * wave + g;
    int s = 0, e = 0;
    if (row < N) { s = rp[row]; e = rp[row + 1]; }
    float a0 = loadF(b1, (size_t)4 * gl,     bf16);
    float a1 = loadF(b1, (size_t)4 * gl + 1, bf16);
    float a2 = loadF(b1, (size_t)4 * gl + 2, bf16);
    float a3 = loadF(b1, (size_t)4 * gl + 3, bf16);
    const int sb = g << 4;
    for (int base = s; base < e; base += 16) {
        int idx = base + gl;
        int cl = 0; float vl = 0.f;
        if (idx < e) ntload(P, idx, &cl, &vl);
        int cnt = min(16, e - base);
        int j = 0;
        for (; j + 4 <= cnt; j += 4) {
            int   c0 = __shfl(cl, sb + j),     c1 = __shfl(cl, sb + j + 1);
            int   c2 = __shfl(cl, sb + j + 2), c3 = __shfl(cl, sb + j + 3);
            float v0 = __shfl(vl, sb + j),     v1 = __shfl(vl, sb + j + 1);
            float v2 = __shfl(vl, sb + j + 2), v3 = __shfl(vl, sb + j + 3);
            uint2 u0 = w1q[c0 * 16 + gl];
            uint2 u1 = w1q[c1 * 16 + gl];
            uint2 u2 = w1q[c2 * 16 + gl];
            uint2 u3 = w1q[c3 * 16 + gl];
            a0 += v0 * bflo(u0.x); a1 += v0 * bfhi(u0.x);
            a2 += v0 * bflo(u0.y); a3 += v0 * bfhi(u0.y);
            a0 += v1 * bflo(u1.x); a1 += v1 * bfhi(u1.x);
            a2 += v1 * bflo(u1.y); a3 += v1 * bfhi(u1.y);
            a0 += v2 * bflo(u2.x); a1 += v2 * bfhi(u2.x);
            a2 += v2 * bflo(u2.y); a3 += v2 * bfhi(u2.y);
            a0 += v3 * bflo(u3.x); a1 += v3 * bfhi(u3.x);
            a2 += v3 * bflo(u3.y); a3 += v3 * bfhi(u3.y);
        }
        for (; j < cnt; j++) {
            int   c = __shfl(cl, sb + j);
            float v = __shfl(vl, sb + j);
            uint2 u = w1q[c * 16 + gl];
            a0 += v * bflo(u.x); a1 += v * bfhi(u.x);
            a2 += v * bflo(u.y); a3 += v * bfhi(u.y);
        }
    }
    if (row < N) hF8[row * 16 + gl] = fp8pack4(a0, a1, a2, a3);
}

// Merged propagation, NO epilogue: h2 = relu(A @ h), fp8 in / fp8 out.
__global__ void gather_edge_h2_kernel(const int* rp, const int2* P,
                                      const unsigned* hF8, unsigned* h2F8,
                                      int N) {
    int wave = (blockIdx.x * blockDim.x + threadIdx.x) >> 6;
    int lane = threadIdx.x & 63;
    int g = lane >> 4, gl = lane & 15;
    int row = 4 * wave + g;
    int s = 0, e = 0;
    if (row < N) { s = rp[N + row]; e = rp[N + row + 1]; }
    float a0 = 0.f, a1 = 0.f, a2 = 0.f, a3 = 0.f;
    const int sb = g << 4;
    for (int base = s; base < e; base += 16) {
        int idx = base + gl;
        int cl = 0; float wl = 0.f;
        if (idx < e) ntload(P, idx, &cl, &wl);
        int cnt = min(16, e - base);
        int j = 0;
        for (; j + 8 <= cnt; j += 8) {
            int   c0 = __shfl(cl, sb + j),     c1 = __shfl(cl, sb + j + 1);
            int   c2 = __shfl(cl, sb + j + 2), c3 = __shfl(cl, sb + j + 3);
            int   c4 = __shfl(cl, sb + j + 4), c5 = __shfl(cl, sb + j + 5);
            int   c6 = __shfl(cl, sb + j + 6), c7 = __shfl(cl, sb + j + 7);
            float w0 = __shfl(wl, sb + j),     w1 = __shfl(wl, sb + j + 1);
            float w2 = __shfl(wl, sb + j + 2), w3 = __shfl(wl, sb + j + 3);
            float w4 = __shfl(wl, sb + j + 4), w5 = __shfl(wl, sb + j + 5);
            float w6 = __shfl(wl, sb + j + 6), w7 = __shfl(wl, sb + j + 7);
            int u0 = (int)hF8[c0 * 16 + gl];
            int u1 = (int)hF8[c1 * 16 + gl];
            int u2 = (int)hF8[c2 * 16 + gl];
            int u3 = (int)hF8[c3 * 16 + gl];
            int u4 = (int)hF8[c4 * 16 + gl];
            int u5 = (int)hF8[c5 * 16 + gl];
            int u6 = (int)hF8[c6 * 16 + gl];
            int u7 = (int)hF8[c7 * 16 + gl];
            a0 += w0 * __builtin_amdgcn_cvt_f32_fp8(u0, 0);
            a1 += w0 * __builtin_amdgcn_cvt_f32_fp8(u0, 1);
            a2 += w0 * __builtin_amdgcn_cvt_f32_fp8(u0, 2);
            a3 += w0 * __builtin_amdgcn_cvt_f32_fp8(u0, 3);
            a0 += w1 * __builtin_amdgcn_cvt_f32_fp8(u1, 0);
            a1 += w1 * __builtin_amdgcn_cvt_f32_fp8(u1, 1);
            a2 += w1 * __builtin_amdgcn_cvt_f32_fp8(u1, 2);
            a3 += w1 * __builtin_amdgcn_cvt_f32_fp8(u1, 3);
            a0 += w2 * __builtin_amdgcn_cvt_f32_fp8(u2, 0);
            a1 += w2 * __builtin_amdgcn_cvt_f32_fp8(u2, 1);
            a2 += w2 * __builtin_amdgcn_cvt_f32_fp8(u2, 2);
            a3 += w2 * __builtin_amdgcn_cvt_f32_fp8(u2, 3);
            a0 += w3 * __builtin_amdgcn_cvt_f32_fp8(u3, 0);
            a1 += w3 * __builtin_amdgcn_cvt_f32_fp8(u3, 1);
            a2 += w3 * __builtin_amdgcn_cvt_f32_fp8(u3, 2);
            a3 += w3 * __builtin_amdgcn_cvt_f32_fp8(u3, 3);
            a0 += w4 * __builtin_amdgcn_cvt_f32_fp8(u4, 0);
            a1 += w4 * __builtin_amdgcn_cvt_f32_fp8(u4, 1);
            a2 += w4 * __builtin_amdgcn_cvt_f32_fp8(u4, 2);
            a3 += w4 * __builtin_amdgcn_cvt_f32_fp8(u4, 3);
            a0 += w5 * __builtin_amdgcn_cvt_f32_fp8(u5, 0);
            a1 += w5 * __builtin_amdgcn_cvt_f32_fp8(u5, 1);
            a2 += w5 * __builtin_amdgcn_cvt_f32_fp8(u5, 2);
            a3 += w5 * __builtin_amdgcn_cvt_f32_fp8(u5, 3);
            a0 += w6 * __builtin_amdgcn_cvt_f32_fp8(u6, 0);
            a1 += w6 * __builtin_amdgcn_cvt_f32_fp8(u6, 1);
            a2 += w6 * __builtin_amdgcn_cvt_f32_fp8(u6, 2);
            a3 += w6 * __builtin_amdgcn_cvt_f32_fp8(u6, 3);
            a0 += w7 * __builtin_amdgcn_cvt_f32_fp8(u7, 0);
            a1 += w7 * __builtin_amdgcn_cvt_f32_fp8(u7, 1);
            a2 += w7 * __builtin_amdgcn_cvt_f32_fp8(u7, 2);
            a3 += w7 * __builtin_amdgcn_cvt_f32_fp8(u7, 3);
        }
        for (; j < cnt; j++) {
            int   c = __shfl(cl, sb + j);
            float w = __shfl(wl, sb + j);
            int u = (int)hF8[c * 16 + gl];
            a0 += w * __builtin_amdgcn_cvt_f32_fp8(u, 0);
            a1 += w * __builtin_amdgcn_cvt_f32_fp8(u, 1);
            a2 += w * __builtin_amdgcn_cvt_f32_fp8(u, 2);
            a3 += w * __builtin_amdgcn_cvt_f32_fp8(u, 3);
        }
    }
    if (row < N)
        h2F8[row * 16 + gl] = fp8pack4(fmaxf(a0, 0.f), fmaxf(a1, 0.f),
                                       fmaxf(a2, 0.f), fmaxf(a3, 0.f));
}

// Shuffle-free, LDS-free dense: z = relu_h2 @ W2 + b2, fp8 out.
__global__ void dense_kernel(const unsigned* h2F8, const void* W2, const void* b2,
                             unsigned char* zb, const int* flags, int N) {
    int bf16 = flags[0];
    int wave = (int)((blockIdx.x * blockDim.x + threadIdx.x) >> 6);
    int lane = threadIdx.x & 63;
    int jj = (lane < LAB) ? lane : 0;
    float w2c[HID];
#pragma unroll
    for (int k = 0; k < HID; k++) w2c[k] = loadF(W2, (size_t)k * LAB + jj, bf16);
    float bias = loadF(b2, (size_t)jj, bf16);
    int r0 = wave * 32;
    int r1 = min(r0 + 32, N);
    for (int r = r0; r < r1; r++) {
        const unsigned* hr = h2F8 + (size_t)r * 16;
        float acc = bias;
#pragma unroll
        for (int k16 = 0; k16 < 16; k16++) {
            int d = (int)hr[k16];
            acc += __builtin_amdgcn_cvt_f32_fp8(d, 0) * w2c[4 * k16];
            acc += __builtin_amdgcn_cvt_f32_fp8(d, 1) * w2c[4 * k16 + 1];
            acc += __builtin_amdgcn_cvt_f32_fp8(d, 2) * w2c[4 * k16 + 2];
            acc += __builtin_amdgcn_cvt_f32_fp8(d, 3) * w2c[4 * k16 + 3];
        }
        if (lane < LAB) {
            int pk = __builtin_amdgcn_cvt_pk_fp8_f32(acc, acc, 0, false);
            zb[(size_t)r * LAB + lane] = (unsigned char)(pk & 0xFF);
        }
    }
}

// 4 rows/wave: z2 = A@z (fp8 gather), fused log_softmax -> out.
__global__ void gather_edge_lsm_kernel(const int* rp, const int2* P,
                                       const unsigned* zF8, void* out,
                                       const int* flags, int N) {
    int bf16 = flags[0];
    int wave = (blockIdx.x * blockDim.x + threadIdx.x) >> 6;
    int lane = threadIdx.x & 63;
    int g = lane >> 4, gl = lane & 15;
    int row = 4 * wave + g;
    int s = 0, e = 0;
    if (row < N) { s = rp[N + row]; e = rp[N + row + 1]; }
    float a0 = 0.f, a1 = 0.f, a2 = 0.f, a3 = 0.f;
    const int sb = g << 4;
    const int act = (gl < 10);
    for (int base = s; base < e; base += 16) {
        int idx = base + gl;
        int cl = 0; float wl = 0.f;
        if (idx < e) ntload(P, idx, &cl, &wl);
        int cnt = min(16, e - base);
        int j = 0;
        for (; j + 4 <= cnt; j += 4) {
            int   c0 = __shfl(cl, sb + j),     c1 = __shfl(cl, sb + j + 1);
            int   c2 = __shfl(cl, sb + j + 2), c3 = __shfl(cl, sb + j + 3);
            float w0 = __shfl(wl, sb + j),     w1 = __shfl(wl, sb + j + 1);
            float w2 = __shfl(wl, sb + j + 2), w3 = __shfl(wl, sb + j + 3);
            if (act) {
                int u0 = (int)zF8[c0 * 10 + gl];
                int u1 = (int)zF8[c1 * 10 + gl];
                int u2 = (int)zF8[c2 * 10 + gl];
                int u3 = (int)zF8[c3 * 10 + gl];
                a0 += w0 * __builtin_amdgcn_cvt_f32_fp8(u0, 0);
                a1 += w0 * __builtin_amdgcn_cvt_f32_fp8(u0, 1);
                a2 += w0 * __builtin_amdgcn_cvt_f32_fp8(u0, 2);
                a3 += w0 * __builtin_amdgcn_cvt_f32_fp8(u0, 3);
                a0 += w1 * __builtin_amdgcn_cvt_f32_fp8(u1, 0);
                a1 += w1 * __builtin_amdgcn_cvt_f32_fp8(u1, 1);
                a2 += w1 * __builtin_amdgcn_cvt_f32_fp8(u1, 2);
                a3 += w1 * __builtin_amdgcn_cvt_f32_fp8(u1, 3);
                a0 += w2 * __builtin_amdgcn_cvt_f32_fp8(u2, 0);
                a1 += w2 * __builtin_amdgcn_cvt_f32_fp8(u2, 1);
                a2 += w2 * __builtin_amdgcn_cvt_f32_fp8(u2, 2);
                a3 += w2 * __builtin_amdgcn_cvt_f32_fp8(u2, 3);
                a0 += w3 * __builtin_amdgcn_cvt_f32_fp8(u3, 0);
                a1 += w3 * __builtin_amdgcn_cvt_f32_fp8(u3, 1);
                a2 += w3 * __builtin_amdgcn_cvt_f32_fp8(u3, 2);
                a3 += w3 * __builtin_amdgcn_cvt_f32_fp8(u3, 3);
            }
        }
        for (; j < cnt; j++) {
            int   c = __shfl(cl, sb + j);
            float w = __shfl(wl, sb + j);
            if (act) {
                int u = (int)zF8[c * 10 + gl];
                a0 += w * __builtin_amdgcn_cvt_f32_fp8(u, 0);
                a1 += w * __builtin_amdgcn_cvt_f32_fp8(u, 1);
                a2 += w * __builtin_amdgcn_cvt_f32_fp8(u, 2);
                a3 += w * __builtin_amdgcn_cvt_f32_fp8(u, 3);
            }
        }
    }
    float m = act ? fmaxf(fmaxf(a0, a1), fmaxf(a2, a3)) : -INFINITY;
#pragma unroll
    for (int off = 8; off; off >>= 1) m = fmaxf(m, __shfl_xor(m, off));
    float es = act ? (__expf(a0 - m) + __expf(a1 - m) + __expf(a2 - m) + __expf(a3 - m)) : 0.f;
#pragma unroll
    for (int off = 8; off; off >>= 1) es += __shfl_xor(es, off);
    float lse = m + __logf(es);
    if (act && row < N) {
        float o0 = a0 - lse, o1 = a1 - lse, o2 = a2 - lse, o3 = a3 - lse;
        if (bf16) {
            ((uint2*)out)[(size_t)row * 10 + gl] =
                make_uint2(bfpack(o0, o1), bfpack(o2, o3));
        } else {
            float4 v = make_float4(o0, o1, o2, o3);
            ((float4*)out)[(size_t)row * 10 + gl] = v;
        }
    }
}

extern "C" void kernel_launch(void* const* d_in, const int* in_sizes, int n_in,
                              void* d_out, int out_size, void* d_ws, size_t ws_size,
                              hipStream_t stream) {
    const void* fidx = d_in[0];
    const void* fval = d_in[1];
    const void* eidx = d_in[2];
    const void* ew   = d_in[3];
    const void* W1   = d_in[4];
    const void* b1   = d_in[5];
    const void* W2   = d_in[6];
    const void* b2   = d_in[7];

    const int nnz = in_sizes[1];          // 2,500,000
    const int nW1 = in_sizes[4];          // 2048*64
    const int nE  = in_sizes[3];          // 1,700,000
    const int N   = out_size / LAB;       // 100,000
    const int M   = 2 * N;
    const int nT  = nnz + nE;
    const int K   = (M + (1 << RSH) - 1) >> RSH;   // 391 buckets
    const int NBLK = (nT + TILE_A - 1) / TILE_A;   // 513 tile blocks

    auto align256 = [](size_t x) { return (x + 255) & ~(size_t)255; };
    char* ws = (char*)d_ws;
    size_t off = 0;
    int*   flags   = (int*)(ws + off);   off += 256;
    // front: hF8 (6.4MB) | h2F8 (6.4MB) | zF8 (4MB); Q (int2, 33.6MB) overlays
    // front and dies before gather_feat writes hF8.
    char*  front   = ws + off;
    unsigned* hF8  = (unsigned*)front;                       // N*16 dwords
    unsigned* h2F8 = hF8 + (size_t)N * 16;                   // N*16 dwords
    unsigned char* zb = (unsigned char*)(h2F8 + (size_t)N * 16);  // N*40 B
    size_t frontBytes = (size_t)N * (64 + 64 + 40);
    size_t qBytes     = (size_t)nT * 8;
    off += align256(frontBytes > qBytes ? frontBytes : qBytes);
    int2*  P       = (int2*)(ws + off);  off += align256((size_t)nT * 8);
    int*   rp      = (int*)(ws + off);   off += align256(((size_t)KMAX << RSH) * 4 + 16);
    uint2* w1q     = (uint2*)(ws + off); off += align256((size_t)nW1 * 2);
    int*   cntB    = (int*)(ws + off);   off += KMAX * 4;
    int*   bqstart = (int*)(ws + off);   off += KMAX * 4;
    int*   cntPB   = (int*)(ws + off);   off += align256((size_t)KMAX * NBLK * 4);
    int2*  Q       = (int2*)front;

    // 1. dtype probe
    probe_kernel<<<1, 64, 0, stream>>>(b1, fidx, flags);

    // 2. zero bucket histogram; stage W1 packed
    zero_kernel<<<1, 256, 0, stream>>>((int4*)cntB, KMAX / 4);
    convw1_kernel<<<(nW1 / 4 + 255) / 256, 256, 0, stream>>>(W1, w1q, flags, nW1 / 4);

    // 3. bucket histogram, tiled like bucketA -> per-(bucket,block) counts
    histB_kernel<<<NBLK, 1024, 0, stream>>>(fidx, eidx, cntB, cntPB,
                                            flags, nnz, nE, N, NBLK);

    // 4. bucket scan -> bucket starts
    scanB_kernel<<<1, KMAX, 0, stream>>>(cntB, bqstart, K);

    // 5. per-bucket scan over blocks -> absolute write base per (bucket,block)
    scanPB_kernel<<<K, 1024, 0, stream>>>(cntPB, bqstart, NBLK);

    // 6. pass A: single-pass scatter into Q using precomputed bases
    bucketA_kernel<<<NBLK, 1024, 0, stream>>>(fidx, fval, eidx, ew, flags,
                                              cntPB, Q, nnz, nE, N, NBLK);

    // 7. pass B: per-bucket row hist/scan in LDS, rp segment, scatter -> P
    bucketB_kernel<<<K, 1024, 0, stream>>>(Q, bqstart, rp, P, nT, K);

    // 8. h = sparse_features @ W1 + b1 -> fp8
    int nwaves = (N + 3) / 4;
    int gblocks = (int)(((size_t)nwaves * 64 + 255) / 256);
    gather_feat_kernel<<<gblocks, 256, 0, stream>>>(rp, P, w1q, b1, hF8, flags, N);

    // 9. h2 = relu(A @ h) -> fp8 (gather-only, no epilogue)
    gather_edge_h2_kernel<<<gblocks, 256, 0, stream>>>(rp, P, hF8, h2F8, N);

    // 10. z = h2 @ W2 + b2 -> fp8 (shuffle-free dense)
    int dwaves = (N + 31) / 32;
    int dblocks = (dwaves * 64 + 255) / 256;
    dense_kernel<<<dblocks, 256, 0, stream>>>(h2F8, W2, b2, zb, flags, N);

    // 11. out = log_softmax(A @ z)
    gather_edge_lsm_kernel<<<gblocks, 256, 0, stream>>>(rp, P, (const unsigned*)zb,
                                                        d_out, flags, N);
}

// Round 4
// 337.108 us; speedup vs baseline: 1.0637x; 1.0186x over previous
//
#include <hip/hip_runtime.h>
#include <hip/hip_bf16.h>

// ---------------------------------------------------------------------------
// GCN forward on MI355X — round 17 (= R16 resubmitted; container failed twice
// on infra, no kernel verdict). R15 post-mortem: removing a whole element
// pass from bucketA saved only 8us (50us left) -> full coalesced load pass
// costs ~8us; the ~42us residual is the scattered 8B Q-store path (64 lines
// per wave-store, 7.3 cyc/transaction) + dependent rank chain. Fix:
// register-held tile + LDS bucket-sort staging, then linear LDS->global flush
// so consecutive lanes write consecutive addresses (runs merge into full-line
// transactions). Dest = delta[b(p)] + p, b(p) via 9-step LDS binary search.
// TILE_A=7168 keeps static LDS at 63.5KB (2 blocks/CU, 32 waves). histB
// retiled to match (586 blocks). Everything downstream unchanged.
// ---------------------------------------------------------------------------

#define HID 64
#define LAB 40
#define RSH 9          // 512 rows per bucket
#define KMAX 512       // max buckets (runtime K = 391)
#define TILE_A 7168    // elements per tile block (1024 threads x 7)
#define EPT 7          // elements per thread in bucketA/histB

__device__ __forceinline__ float loadF(const void* p, size_t i, int bf16) {
    if (bf16) return __bfloat162float(((const __hip_bfloat16*)p)[i]);
    return ((const float*)p)[i];
}

__device__ __forceinline__ int loadI(const void* p, size_t i, int i64) {
    if (i64) return (int)(((const long long*)p)[i]);
    return ((const int*)p)[i];
}

// packed bf16x2 helpers
__device__ __forceinline__ float bflo(unsigned v) { return __uint_as_float(v << 16); }
__device__ __forceinline__ float bfhi(unsigned v) { return __uint_as_float(v & 0xFFFF0000u); }
__device__ __forceinline__ unsigned bfr16(float x) {
    unsigned u = __float_as_uint(x);
    return (u + 0x7FFFu + ((u >> 16) & 1u)) >> 16;
}
__device__ __forceinline__ unsigned bfpack(float lo, float hi) {
    return bfr16(lo) | (bfr16(hi) << 16);
}

// fp8 e4m3 HW converts
__device__ __forceinline__ unsigned fp8pack4(float a, float b, float c, float d) {
    int r = __builtin_amdgcn_cvt_pk_fp8_f32(a, b, 0, false);
    r = __builtin_amdgcn_cvt_pk_fp8_f32(c, d, r, true);
    return (unsigned)r;
}

// nontemporal int2 load (keep P streams out of L2)
__device__ __forceinline__ void ntload(const int2* P, int idx, int* c, float* w) {
    long long raw = __builtin_nontemporal_load((const long long*)P + idx);
    *c = (int)(unsigned)(raw & 0xFFFFFFFFll);
    *w = __int_as_float((int)(raw >> 32));
}

// dtype probe (validated R1-R15)
__global__ void probe_kernel(const void* b1p, const void* fidxp, int* flags) {
    if (threadIdx.x == 0 && blockIdx.x == 0) {
        const unsigned short* u = (const unsigned short*)b1p;
        int bf16 = 1;
        for (int i = 0; i < 64; i += 2)
            if ((unsigned short)(u[i] & 0x7FFF) >= 0x3E80) { bf16 = 0; break; }
        const int* ip = (const int*)fidxp;
        int i64 = 1;
        for (int i = 1; i < 128; i += 2)
            if (ip[i] != 0) { i64 = 0; break; }
        flags[0] = bf16; flags[1] = i64; flags[2] = 0; flags[3] = 0;
    }
}

__global__ void zero_kernel(int4* p, int n4) {
    int i = blockIdx.x * blockDim.x + threadIdx.x;
    if (i < n4) p[i] = make_int4(0, 0, 0, 0);
}

// W1 -> packed bf16 staging: entry i = features 4i..4i+3 (uint2)
__global__ void convw1_kernel(const void* W1, uint2* w1q, const int* flags, int ne) {
    int i = blockIdx.x * blockDim.x + threadIdx.x;
    if (i < ne) {
        float f0 = loadF(W1, (size_t)4 * i,     flags[0]);
        float f1 = loadF(W1, (size_t)4 * i + 1, flags[0]);
        float f2 = loadF(W1, (size_t)4 * i + 2, flags[0]);
        float f3 = loadF(W1, (size_t)4 * i + 3, flags[0]);
        w1q[i] = make_uint2(bfpack(f0, f1), bfpack(f2, f3));
    }
}

// Bucket histogram, tiled EXACTLY like bucketA (one block per TILE_A run).
// Emits per-(bucket,block) counts cntPB[b*nblk+blk] + global totals cntB.
__global__ __launch_bounds__(1024)
void histB_kernel(const void* fidx, const void* eidx, int* cntB, int* cntPB,
                  const int* flags, int nnz, int nE, int N, int nblk) {
    __shared__ int lh[KMAX];
    if (threadIdx.x < KMAX) lh[threadIdx.x] = 0;
    __syncthreads();
    const int i64 = flags[1];
    const int nT = nnz + nE;
    const int base = blockIdx.x * TILE_A;
#pragma unroll
    for (int k = 0; k < EPT; k++) {
        int i = base + k * 1024 + threadIdx.x;
        if (i < nT) {
            int grow = (i < nnz) ? loadI(fidx, (size_t)i, i64)
                                 : N + loadI(eidx, (size_t)(i - nnz), i64);
            atomicAdd(&lh[grow >> RSH], 1);
        }
    }
    __syncthreads();
    if (threadIdx.x < KMAX) {
        int c = lh[threadIdx.x];
        cntPB[(size_t)threadIdx.x * nblk + blockIdx.x] = c;
        if (c) atomicAdd(&cntB[threadIdx.x], c);
    }
}

// single-block exclusive scan of bucket counts -> bqstart
__global__ void scanB_kernel(const int* cntB, int* bqstart, int K) {
    __shared__ int s[KMAX];
    int t = threadIdx.x;
    int x = (t < K) ? cntB[t] : 0;
    s[t] = x;
    __syncthreads();
    for (int off = 1; off < KMAX; off <<= 1) {
        int v = (t >= off) ? s[t - off] : 0;
        __syncthreads();
        s[t] += v;
        __syncthreads();
    }
    if (t < K) bqstart[t] = s[t] - x;
}

// one block per bucket: exclusive scan over the nblk per-block counts,
// rebased by bqstart -> cntPB becomes absolute write base per (bucket,block)
__global__ __launch_bounds__(1024)
void scanPB_kernel(int* cntPB, const int* bqstart, int nblk) {
    __shared__ int s[1024];
    const int b = blockIdx.x;
    const int t = threadIdx.x;
    int x = (t < nblk) ? cntPB[(size_t)b * nblk + t] : 0;
    s[t] = x;
    __syncthreads();
    for (int off = 1; off < 1024; off <<= 1) {
        int v = (t >= off) ? s[t - off] : 0;
        __syncthreads();
        s[t] += v;
        __syncthreads();
    }
    if (t < nblk) cntPB[(size_t)b * nblk + t] = bqstart[b] + s[t] - x;
}

// Pass A: register-held tile -> LDS bucket-sort -> coalesced flush to Q.
// stage 56KB + hist 2KB + lofs 2.05KB + delta 2KB = 63.5KB LDS, 2 blocks/CU.
__global__ __launch_bounds__(1024)
void bucketA_kernel(const void* fidx, const void* fval,
                    const void* eidx, const void* ew,
                    const int* flags, const int* cntPB, int2* Q,
                    int nnz, int nE, int N, int nblk) {
    __shared__ int2 stage[TILE_A];
    __shared__ int hist[KMAX];
    __shared__ int lofs[KMAX + 1];
    __shared__ int delta[KMAX];
    const int i64 = flags[1], bf16 = flags[0];
    const int nT = nnz + nE;
    const int base = blockIdx.x * TILE_A;
    const int t = threadIdx.x;
    if (t < KMAX) hist[t] = 0;
    __syncthreads();

    // phase 1: load tile into registers, LDS histogram with returned rank
    int key[EPT]; float val[EPT]; int bk[EPT]; int rk[EPT];
#pragma unroll
    for (int k = 0; k < EPT; k++) {
        int i = base + k * 1024 + t;
        bk[k] = -1; rk[k] = 0; key[k] = 0; val[k] = 0.f;
        if (i < nT) {
            int grow, c; float v;
            if (i < nnz) {
                grow = loadI(fidx, (size_t)i, i64);
                c    = loadI(fidx, (size_t)nnz + i, i64);
                v    = loadF(fval, (size_t)i, bf16);
            } else {
                int j = i - nnz;
                grow = N + loadI(eidx, (size_t)j, i64);
                c    = loadI(eidx, (size_t)nE + j, i64);
                v    = loadF(ew, (size_t)j, bf16);
            }
            int b = grow >> RSH;
            bk[k]  = b;
            key[k] = ((grow & ((1 << RSH) - 1)) << 17) | c;
            val[k] = v;
            rk[k]  = atomicAdd(&hist[b], 1);
        }
    }
    __syncthreads();

    // phase 2: inclusive scan of counts (scratch in delta), then
    // lofs = exclusive scan (+ sentinel), delta = gbase - lofs
    int cnt = (t < KMAX) ? hist[t] : 0;
    if (t < KMAX) delta[t] = cnt;
    __syncthreads();
    for (int off2 = 1; off2 < KMAX; off2 <<= 1) {
        int v2 = (t >= off2 && t < KMAX) ? delta[t - off2] : 0;
        __syncthreads();
        if (t < KMAX) delta[t] += v2;
        __syncthreads();
    }
    if (t < KMAX) {
        int incl = delta[t];
        int excl = incl - cnt;
        lofs[t] = excl;
        if (t == KMAX - 1) lofs[KMAX] = incl;
        delta[t] = cntPB[(size_t)t * nblk + blockIdx.x] - excl;
    }
    __syncthreads();

    // phase 3: stage into LDS in bucket-sorted order
#pragma unroll
    for (int k = 0; k < EPT; k++) {
        if (bk[k] >= 0)
            stage[lofs[bk[k]] + rk[k]] = make_int2(key[k], __float_as_int(val[k]));
    }
    __syncthreads();

    // phase 4: linear flush; dest(p) = delta[b(p)] + p, b via binary search
    const int total = min(TILE_A, nT - base);
    for (int p = t; p < total; p += 1024) {
        int b = 0;
#pragma unroll
        for (int step = KMAX / 2; step; step >>= 1)
            if (lofs[b + step] <= p) b += step;
        Q[delta[b] + p] = stage[p];
    }
}

// Pass B: one 1024-thread block per bucket; LDS row hist + scan -> rp segment,
// scatter to P with LDS rank cursors. Scan is 512-wide (rows/bucket), guarded.
__global__ __launch_bounds__(1024)
void bucketB_kernel(const int2* Q, const int* bqstart, int* rp,
                    int2* P, int nT, int K) {
    __shared__ int lh[1 << RSH];
    __shared__ int s[1 << RSH];
    __shared__ int lstart[1 << RSH];
    const int b = blockIdx.x;
    const int t = threadIdx.x;
    const int start = bqstart[b];
    const int end = (b == K - 1) ? nT : bqstart[b + 1];
    if (t < (1 << RSH)) lh[t] = 0;
    __syncthreads();
    for (int i = start + t; i < end; i += 1024)
        atomicAdd(&lh[((unsigned)Q[i].x) >> 17], 1);
    __syncthreads();
    int x = (t < (1 << RSH)) ? lh[t] : 0;
    if (t < (1 << RSH)) s[t] = x;
    __syncthreads();
    for (int off = 1; off < (1 << RSH); off <<= 1) {
        int v = (t >= off && t < (1 << RSH)) ? s[t - off] : 0;
        __syncthreads();
        if (t < (1 << RSH)) s[t] += v;
        __syncthreads();
    }
    if (t < (1 << RSH)) {
        int rowstart = start + s[t] - x;
        rp[(b << RSH) + t] = rowstart;
        lstart[t] = rowstart;
        lh[t] = 0;
    }
    __syncthreads();
    for (int i = start + t; i < end; i += 1024) {
        int2 el = Q[i];
        int lr = ((unsigned)el.x) >> 17;
        int rank = atomicAdd(&lh[lr], 1);
        P[lstart[lr] + rank] = make_int2(el.x & 0x1FFFF, el.y);
    }
}

// 4 rows/wave feat gather: h = b1 + sum v*W1[c], stored fp8 (row*16+gl dword).
__global__ void gather_feat_kernel(const int* rp, const int2* P,
                                   const uint2* w1q, const void* b1,
                                   unsigned* hF8, const int* flags, int N) {
    int bf16 = flags[0];
    int wave = (blockIdx.x * blockDim.x + threadIdx.x) >> 6;
    int lane = threadIdx.x & 63;
    int g = lane >> 4, gl = lane & 15;
    int row = 4 * wave + g;
    int s = 0, e = 0;
    if (row < N) { s = rp[row]; e = rp[row + 1]; }
    float a0 = loadF(b1, (size_t)4 * gl,     bf16);
    float a1 = loadF(b1, (size_t)4 * gl + 1, bf16);
    float a2 = loadF(b1, (size_t)4 * gl + 2, bf16);
    float a3 = loadF(b1, (size_t)4 * gl + 3, bf16);
    const int sb = g << 4;
    for (int base = s; base < e; base += 16) {
        int idx = base + gl;
        int cl = 0; float vl = 0.f;
        if (idx < e) ntload(P, idx, &cl, &vl);
        int cnt = min(16, e - base);
        int j = 0;
        for (; j + 4 <= cnt; j += 4) {
            int   c0 = __shfl(cl, sb + j),     c1 = __shfl(cl, sb + j + 1);
            int   c2 = __shfl(cl, sb + j + 2), c3 = __shfl(cl, sb + j + 3);
            float v0 = __shfl(vl, sb + j),     v1 = __shfl(vl, sb + j + 1);
            float v2 = __shfl(vl, sb + j + 2), v3 = __shfl(vl, sb + j + 3);
            uint2 u0 = w1q[c0 * 16 + gl];
            uint2 u1 = w1q[c1 * 16 + gl];
            uint2 u2 = w1q[c2 * 16 + gl];
            uint2 u3 = w1q[c3 * 16 + gl];
            a0 += v0 * bflo(u0.x); a1 += v0 * bfhi(u0.x);
            a2 += v0 * bflo(u0.y); a3 += v0 * bfhi(u0.y);
            a0 += v1 * bflo(u1.x); a1 += v1 * bfhi(u1.x);
            a2 += v1 * bflo(u1.y); a3 += v1 * bfhi(u1.y);
            a0 += v2 * bflo(u2.x); a1 += v2 * bfhi(u2.x);
            a2 += v2 * bflo(u2.y); a3 += v2 * bfhi(u2.y);
            a0 += v3 * bflo(u3.x); a1 += v3 * bfhi(u3.x);
            a2 += v3 * bflo(u3.y); a3 += v3 * bfhi(u3.y);
        }
        for (; j < cnt; j++) {
            int   c = __shfl(cl, sb + j);
            float v = __shfl(vl, sb + j);
            uint2 u = w1q[c * 16 + gl];
            a0 += v * bflo(u.x); a1 += v * bfhi(u.x);
            a2 += v * bflo(u.y); a3 += v * bfhi(u.y);
        }
    }
    if (row < N) hF8[row * 16 + gl] = fp8pack4(a0, a1, a2, a3);
}

// Merged propagation, NO epilogue: h2 = relu(A @ h), fp8 in / fp8 out.
__global__ void gather_edge_h2_kernel(const int* rp, const int2* P,
                                      const unsigned* hF8, unsigned* h2F8,
                                      int N) {
    int wave = (blockIdx.x * blockDim.x + threadIdx.x) >> 6;
    int lane = threadIdx.x & 63;
    int g = lane >> 4, gl = lane & 15;
    int row = 4 * wave + g;
    int s = 0, e = 0;
    if (row < N) { s = rp[N + row]; e = rp[N + row + 1]; }
    float a0 = 0.f, a1 = 0.f, a2 = 0.f, a3 = 0.f;
    const int sb = g << 4;
    for (int base = s; base < e; base += 16) {
        int idx = base + gl;
        int cl = 0; float wl = 0.f;
        if (idx < e) ntload(P, idx, &cl, &wl);
        int cnt = min(16, e - base);
        int j = 0;
        for (; j + 8 <= cnt; j += 8) {
            int   c0 = __shfl(cl, sb + j),     c1 = __shfl(cl, sb + j + 1);
            int   c2 = __shfl(cl, sb + j + 2), c3 = __shfl(cl, sb + j + 3);
            int   c4 = __shfl(cl, sb + j + 4), c5 = __shfl(cl, sb + j + 5);
            int   c6 = __shfl(cl, sb + j + 6), c7 = __shfl(cl, sb + j + 7);
            float w0 = __shfl(wl, sb + j),     w1 = __shfl(wl, sb + j + 1);
            float w2 = __shfl(wl, sb + j + 2), w3 = __shfl(wl, sb + j + 3);
            float w4 = __shfl(wl, sb + j + 4), w5 = __shfl(wl, sb + j + 5);
            float w6 = __shfl(wl, sb + j + 6), w7 = __shfl(wl, sb + j + 7);
            int u0 = (int)hF8[c0 * 16 + gl];
            int u1 = (int)hF8[c1 * 16 + gl];
            int u2 = (int)hF8[c2 * 16 + gl];
            int u3 = (int)hF8[c3 * 16 + gl];
            int u4 = (int)hF8[c4 * 16 + gl];
            int u5 = (int)hF8[c5 * 16 + gl];
            int u6 = (int)hF8[c6 * 16 + gl];
            int u7 = (int)hF8[c7 * 16 + gl];
            a0 += w0 * __builtin_amdgcn_cvt_f32_fp8(u0, 0);
            a1 += w0 * __builtin_amdgcn_cvt_f32_fp8(u0, 1);
            a2 += w0 * __builtin_amdgcn_cvt_f32_fp8(u0, 2);
            a3 += w0 * __builtin_amdgcn_cvt_f32_fp8(u0, 3);
            a0 += w1 * __builtin_amdgcn_cvt_f32_fp8(u1, 0);
            a1 += w1 * __builtin_amdgcn_cvt_f32_fp8(u1, 1);
            a2 += w1 * __builtin_amdgcn_cvt_f32_fp8(u1, 2);
            a3 += w1 * __builtin_amdgcn_cvt_f32_fp8(u1, 3);
            a0 += w2 * __builtin_amdgcn_cvt_f32_fp8(u2, 0);
            a1 += w2 * __builtin_amdgcn_cvt_f32_fp8(u2, 1);
            a2 += w2 * __builtin_amdgcn_cvt_f32_fp8(u2, 2);
            a3 += w2 * __builtin_amdgcn_cvt_f32_fp8(u2, 3);
            a0 += w3 * __builtin_amdgcn_cvt_f32_fp8(u3, 0);
            a1 += w3 * __builtin_amdgcn_cvt_f32_fp8(u3, 1);
            a2 += w3 * __builtin_amdgcn_cvt_f32_fp8(u3, 2);
            a3 += w3 * __builtin_amdgcn_cvt_f32_fp8(u3, 3);
            a0 += w4 * __builtin_amdgcn_cvt_f32_fp8(u4, 0);
            a1 += w4 * __builtin_amdgcn_cvt_f32_fp8(u4, 1);
            a2 += w4 * __builtin_amdgcn_cvt_f32_fp8(u4, 2);
            a3 += w4 * __builtin_amdgcn_cvt_f32_fp8(u4, 3);
            a0 += w5 * __builtin_amdgcn_cvt_f32_fp8(u5, 0);
            a1 += w5 * __builtin_amdgcn_cvt_f32_fp8(u5, 1);
            a2 += w5 * __builtin_amdgcn_cvt_f32_fp8(u5, 2);
            a3 += w5 * __builtin_amdgcn_cvt_f32_fp8(u5, 3);
            a0 += w6 * __builtin_amdgcn_cvt_f32_fp8(u6, 0);
            a1 += w6 * __builtin_amdgcn_cvt_f32_fp8(u6, 1);
            a2 += w6 * __builtin_amdgcn_cvt_f32_fp8(u6, 2);
            a3 += w6 * __builtin_amdgcn_cvt_f32_fp8(u6, 3);
            a0 += w7 * __builtin_amdgcn_cvt_f32_fp8(u7, 0);
            a1 += w7 * __builtin_amdgcn_cvt_f32_fp8(u7, 1);
            a2 += w7 * __builtin_amdgcn_cvt_f32_fp8(u7, 2);
            a3 += w7 * __builtin_amdgcn_cvt_f32_fp8(u7, 3);
        }
        for (; j < cnt; j++) {
            int   c = __shfl(cl, sb + j);
            float w = __shfl(wl, sb + j);
            int u = (int)hF8[c * 16 + gl];
            a0 += w * __builtin_amdgcn_cvt_f32_fp8(u, 0);
            a1 += w * __builtin_amdgcn_cvt_f32_fp8(u, 1);
            a2 += w * __builtin_amdgcn_cvt_f32_fp8(u, 2);
            a3 += w * __builtin_amdgcn_cvt_f32_fp8(u, 3);
        }
    }
    if (row < N)
        h2F8[row * 16 + gl] = fp8pack4(fmaxf(a0, 0.f), fmaxf(a1, 0.f),
                                       fmaxf(a2, 0.f), fmaxf(a3, 0.f));
}

// Shuffle-free, LDS-free dense: z = relu_h2 @ W2 + b2, fp8 out.
__global__ void dense_kernel(const unsigned* h2F8, const void* W2, const void* b2,
                             unsigned char* zb, const int* flags, int N) {
    int bf16 = flags[0];
    int wave = (int)((blockIdx.x * blockDim.x + threadIdx.x) >> 6);
    int lane = threadIdx.x & 63;
    int jj = (lane < LAB) ? lane : 0;
    float w2c[HID];
#pragma unroll
    for (int k = 0; k < HID; k++) w2c[k] = loadF(W2, (size_t)k * LAB + jj, bf16);
    float bias = loadF(b2, (size_t)jj, bf16);
    int r0 = wave * 32;
    int r1 = min(r0 + 32, N);
    for (int r = r0; r < r1; r++) {
        const unsigned* hr = h2F8 + (size_t)r * 16;
        float acc = bias;
#pragma unroll
        for (int k16 = 0; k16 < 16; k16++) {
            int d = (int)hr[k16];
            acc += __builtin_amdgcn_cvt_f32_fp8(d, 0) * w2c[4 * k16];
            acc += __builtin_amdgcn_cvt_f32_fp8(d, 1) * w2c[4 * k16 + 1];
            acc += __builtin_amdgcn_cvt_f32_fp8(d, 2) * w2c[4 * k16 + 2];
            acc += __builtin_amdgcn_cvt_f32_fp8(d, 3) * w2c[4 * k16 + 3];
        }
        if (lane < LAB) {
            int pk = __builtin_amdgcn_cvt_pk_fp8_f32(acc, acc, 0, false);
            zb[(size_t)r * LAB + lane] = (unsigned char)(pk & 0xFF);
        }
    }
}

// 4 rows/wave: z2 = A@z (fp8 gather), fused log_softmax -> out.
__global__ void gather_edge_lsm_kernel(const int* rp, const int2* P,
                                       const unsigned* zF8, void* out,
                                       const int* flags, int N) {
    int bf16 = flags[0];
    int wave = (blockIdx.x * blockDim.x + threadIdx.x) >> 6;
    int lane = threadIdx.x & 63;
    int g = lane >> 4, gl = lane & 15;
    int row = 4 * wave + g;
    int s = 0, e = 0;
    if (row < N) { s = rp[N + row]; e = rp[N + row + 1]; }
    float a0 = 0.f, a1 = 0.f, a2 = 0.f, a3 = 0.f;
    const int sb = g << 4;
    const int act = (gl < 10);
    for (int base = s; base < e; base += 16) {
        int idx = base + gl;
        int cl = 0; float wl = 0.f;
        if (idx < e) ntload(P, idx, &cl, &wl);
        int cnt = min(16, e - base);
        int j = 0;
        for (; j + 4 <= cnt; j += 4) {
            int   c0 = __shfl(cl, sb + j),     c1 = __shfl(cl, sb + j + 1);
            int   c2 = __shfl(cl, sb + j + 2), c3 = __shfl(cl, sb + j + 3);
            float w0 = __shfl(wl, sb + j),     w1 = __shfl(wl, sb + j + 1);
            float w2 = __shfl(wl, sb + j + 2), w3 = __shfl(wl, sb + j + 3);
            if (act) {
                int u0 = (int)zF8[c0 * 10 + gl];
                int u1 = (int)zF8[c1 * 10 + gl];
                int u2 = (int)zF8[c2 * 10 + gl];
                int u3 = (int)zF8[c3 * 10 + gl];
                a0 += w0 * __builtin_amdgcn_cvt_f32_fp8(u0, 0);
                a1 += w0 * __builtin_amdgcn_cvt_f32_fp8(u0, 1);
                a2 += w0 * __builtin_amdgcn_cvt_f32_fp8(u0, 2);
                a3 += w0 * __builtin_amdgcn_cvt_f32_fp8(u0, 3);
                a0 += w1 * __builtin_amdgcn_cvt_f32_fp8(u1, 0);
                a1 += w1 * __builtin_amdgcn_cvt_f32_fp8(u1, 1);
                a2 += w1 * __builtin_amdgcn_cvt_f32_fp8(u1, 2);
                a3 += w1 * __builtin_amdgcn_cvt_f32_fp8(u1, 3);
                a0 += w2 * __builtin_amdgcn_cvt_f32_fp8(u2, 0);
                a1 += w2 * __builtin_amdgcn_cvt_f32_fp8(u2, 1);
                a2 += w2 * __builtin_amdgcn_cvt_f32_fp8(u2, 2);
                a3 += w2 * __builtin_amdgcn_cvt_f32_fp8(u2, 3);
                a0 += w3 * __builtin_amdgcn_cvt_f32_fp8(u3, 0);
                a1 += w3 * __builtin_amdgcn_cvt_f32_fp8(u3, 1);
                a2 += w3 * __builtin_amdgcn_cvt_f32_fp8(u3, 2);
                a3 += w3 * __builtin_amdgcn_cvt_f32_fp8(u3, 3);
            }
        }
        for (; j < cnt; j++) {
            int   c = __shfl(cl, sb + j);
            float w = __shfl(wl, sb + j);
            if (act) {
                int u = (int)zF8[c * 10 + gl];
                a0 += w * __builtin_amdgcn_cvt_f32_fp8(u, 0);
                a1 += w * __builtin_amdgcn_cvt_f32_fp8(u, 1);
                a2 += w * __builtin_amdgcn_cvt_f32_fp8(u, 2);
                a3 += w * __builtin_amdgcn_cvt_f32_fp8(u, 3);
            }
        }
    }
    float m = act ? fmaxf(fmaxf(a0, a1), fmaxf(a2, a3)) : -INFINITY;
#pragma unroll
    for (int off = 8; off; off >>= 1) m = fmaxf(m, __shfl_xor(m, off));
    float es = act ? (__expf(a0 - m) + __expf(a1 - m) + __expf(a2 - m) + __expf(a3 - m)) : 0.f;
#pragma unroll
    for (int off = 8; off; off >>= 1) es += __shfl_xor(es, off);
    float lse = m + __logf(es);
    if (act && row < N) {
        float o0 = a0 - lse, o1 = a1 - lse, o2 = a2 - lse, o3 = a3 - lse;
        if (bf16) {
            ((uint2*)out)[(size_t)row * 10 + gl] =
                make_uint2(bfpack(o0, o1), bfpack(o2, o3));
        } else {
            float4 v = make_float4(o0, o1, o2, o3);
            ((float4*)out)[(size_t)row * 10 + gl] = v;
        }
    }
}

extern "C" void kernel_launch(void* const* d_in, const int* in_sizes, int n_in,
                              void* d_out, int out_size, void* d_ws, size_t ws_size,
                              hipStream_t stream) {
    const void* fidx = d_in[0];
    const void* fval = d_in[1];
    const void* eidx = d_in[2];
    const void* ew   = d_in[3];
    const void* W1   = d_in[4];
    const void* b1   = d_in[5];
    const void* W2   = d_in[6];
    const void* b2   = d_in[7];

    const int nnz = in_sizes[1];          // 2,500,000
    const int nW1 = in_sizes[4];          // 2048*64
    const int nE  = in_sizes[3];          // 1,700,000
    const int N   = out_size / LAB;       // 100,000
    const int M   = 2 * N;
    const int nT  = nnz + nE;
    const int K   = (M + (1 << RSH) - 1) >> RSH;   // 391 buckets
    const int NBLK = (nT + TILE_A - 1) / TILE_A;   // 586 tile blocks

    auto align256 = [](size_t x) { return (x + 255) & ~(size_t)255; };
    char* ws = (char*)d_ws;
    size_t off = 0;
    int*   flags   = (int*)(ws + off);   off += 256;
    // front: hF8 (6.4MB) | h2F8 (6.4MB) | zF8 (4MB); Q (int2, 33.6MB) overlays
    // front and dies before gather_feat writes hF8.
    char*  front   = ws + off;
    unsigned* hF8  = (unsigned*)front;                       // N*16 dwords
    unsigned* h2F8 = hF8 + (size_t)N * 16;                   // N*16 dwords
    unsigned char* zb = (unsigned char*)(h2F8 + (size_t)N * 16);  // N*40 B
    size_t frontBytes = (size_t)N * (64 + 64 + 40);
    size_t qBytes     = (size_t)nT * 8;
    off += align256(frontBytes > qBytes ? frontBytes : qBytes);
    int2*  P       = (int2*)(ws + off);  off += align256((size_t)nT * 8);
    int*   rp      = (int*)(ws + off);   off += align256(((size_t)KMAX << RSH) * 4 + 16);
    uint2* w1q     = (uint2*)(ws + off); off += align256((size_t)nW1 * 2);
    int*   cntB    = (int*)(ws + off);   off += KMAX * 4;
    int*   bqstart = (int*)(ws + off);   off += KMAX * 4;
    int*   cntPB   = (int*)(ws + off);   off += align256((size_t)KMAX * NBLK * 4);
    int2*  Q       = (int2*)front;

    // 1. dtype probe
    probe_kernel<<<1, 64, 0, stream>>>(b1, fidx, flags);

    // 2. zero bucket histogram; stage W1 packed
    zero_kernel<<<1, 256, 0, stream>>>((int4*)cntB, KMAX / 4);
    convw1_kernel<<<(nW1 / 4 + 255) / 256, 256, 0, stream>>>(W1, w1q, flags, nW1 / 4);

    // 3. bucket histogram, tiled like bucketA -> per-(bucket,block) counts
    histB_kernel<<<NBLK, 1024, 0, stream>>>(fidx, eidx, cntB, cntPB,
                                            flags, nnz, nE, N, NBLK);

    // 4. bucket scan -> bucket starts
    scanB_kernel<<<1, KMAX, 0, stream>>>(cntB, bqstart, K);

    // 5. per-bucket scan over blocks -> absolute write base per (bucket,block)
    scanPB_kernel<<<K, 1024, 0, stream>>>(cntPB, bqstart, NBLK);

    // 6. pass A: register tile -> LDS bucket-sort -> coalesced scatter into Q
    bucketA_kernel<<<NBLK, 1024, 0, stream>>>(fidx, fval, eidx, ew, flags,
                                              cntPB, Q, nnz, nE, N, NBLK);

    // 7. pass B: per-bucket row hist/scan in LDS, rp segment, scatter -> P
    bucketB_kernel<<<K, 1024, 0, stream>>>(Q, bqstart, rp, P, nT, K);

    // 8. h = sparse_features @ W1 + b1 -> fp8
    int nwaves = (N + 3) / 4;
    int gblocks = (int)(((size_t)nwaves * 64 + 255) / 256);
    gather_feat_kernel<<<gblocks, 256, 0, stream>>>(rp, P, w1q, b1, hF8, flags, N);

    // 9. h2 = relu(A @ h) -> fp8 (gather-only, no epilogue)
    gather_edge_h2_kernel<<<gblocks, 256, 0, stream>>>(rp, P, hF8, h2F8, N);

    // 10. z = h2 @ W2 + b2 -> fp8 (shuffle-free dense)
    int dwaves = (N + 31) / 32;
    int dblocks = (dwaves * 64 + 255) / 256;
    dense_kernel<<<dblocks, 256, 0, stream>>>(h2F8, W2, b2, zb, flags, N);

    // 11. out = log_softmax(A @ z)
    gather_edge_lsm_kernel<<<gblocks, 256, 0, stream>>>(rp, P, (const unsigned*)zb,
                                                        d_out, flags, N);
}